// Round 12
// baseline (76.298 us; speedup 1.0000x reference)
//
#include <hip/hip_runtime.h>
#include <math.h>

typedef short bf16x8 __attribute__((ext_vector_type(8)));
typedef float f32x4 __attribute__((ext_vector_type(4)));
typedef unsigned int uint32;

#define BETA 10.0f
#define THRESH -88.0f
// PER-ELEMENT 32-dim certificate, fused into the MFMA:
//   proxy = MFMA(x_bf16, 20*c_bf16, C = -10*||x_r||^2_32) = 20*(x.c)_32 - 10*||x_r||^2_32
//   bct   = max(proxy) + (-10*||c_j||^2_32)
// = -10*d2_32 + eps, |eps| <= ~10 (bf16 rtne dot, 20x-scaled B, Gram-diag norms).
// true arg64 = -10*d2_64 <= -10*d2_32 <= proxy+c2+10. Skip when <= -88 =>
// arg64 <= -78 => contribution <= exp(-78)*1024*0.02 ~ 2e-32 << 1.5e-2.
// P(fire) ~ P(d2_32 < ~8.8) ~ 1.6e-9/pair -> ~0.1 expected over 67M pairs;
// a firing costs one per-ct cold block (16 cols, exact fp32 over 64 dims).

// LDS map (73.75 KB -> 2 blocks/CU)
#define C_OFF   0        // 65536 B: centers lo-32-dim bf16 (x20), chunk layout
#define XB_OFF  65536    // 8192 B: x lo-32-dim bf16, chunk layout (128 rows)
#define RED_OFF 73728    // 1536 B: out accumulator [128][3]
#define LDS_TOT 75264

__device__ __forceinline__ uint32 f2bf_rtne(float f) {
    uint32 u = __float_as_uint(f);
    u += 0x7FFFu + ((u >> 16) & 1u);
    return u >> 16;
}
__device__ __forceinline__ uint32 pk_rtne(float a, float b) {
    return f2bf_rtne(a) | (f2bf_rtne(b) << 16);
}
__device__ __forceinline__ f32x4 vmax4(f32x4 a, f32x4 b) {
    f32x4 r;
    r[0] = fmaxf(a[0], b[0]); r[1] = fmaxf(a[1], b[1]);
    r[2] = fmaxf(a[2], b[2]); r[3] = fmaxf(a[3], b[3]);
    return r;
}
#define MFMA __builtin_amdgcn_mfma_f32_16x16x32_bf16

// Single kernel. Block = 128 rows x 1024 centers; certificate over dims
// 0..31, exact fp32 fallback over all 64. 512 thr = 8 waves; wave = all
// 128 rows x 128-col group. Grid 512 = 2 blocks/CU; TWO barriers total.
__global__ __launch_bounds__(512, 4) void rbfn_fused(
    const float* __restrict__ x,
    const float* __restrict__ centers,
    const float* __restrict__ W,
    const float* __restrict__ bias,
    float* __restrict__ out)
{
    __shared__ __align__(16) char lds[LDS_TOT];

    const int tid = threadIdx.x;
    const int wv = tid >> 6;
    const int lane = tid & 63;
    const int quad = lane >> 4;
    const int l15 = lane & 15;
    const int row0 = blockIdx.x * 128;
    const f32x4 z = {0.f, 0.f, 0.f, 0.f};

    // ---- stage centers lo-half, PRE-SCALED by 20 -> bf16 chunk layout ----
    #pragma unroll
    for (int i = 0; i < 16; ++i) {
        const int f = i * 512 + tid;
        const int j = f >> 3, sg = f & 7;
        const float4 v = *((const float4*)centers + j * 16 + sg);
        uint2 q;
        q.x = pk_rtne(20.f * v.x, 20.f * v.y);
        q.y = pk_rtne(20.f * v.z, 20.f * v.w);
        *(uint2*)(lds + C_OFF + (j >> 4) * 1024 + (sg >> 1) * 256 +
                  (j & 15) * 16 + (sg & 1) * 8) = q;
    }
    // ---- stage x lo-half (128 rows) -> bf16 chunk layout ----
    #pragma unroll
    for (int i = 0; i < 2; ++i) {
        const int f = i * 512 + tid;
        const int r = f >> 3, sg = f & 7;
        const float4 v = *((const float4*)(x + (size_t)row0 * 64) + r * 16 + sg);
        uint2 q; q.x = pk_rtne(v.x, v.y); q.y = pk_rtne(v.z, v.w);
        *(uint2*)(lds + XB_OFF + (r >> 4) * 1024 + (sg >> 1) * 256 +
                  (r & 15) * 16 + (sg & 1) * 8) = q;
    }

    // ---- exact fp32 x@Wx^T + bias -> red (global reads; overlaps staging) ----
    {
        const int r = tid >> 2, e = tid & 3;
        const float4* xr = (const float4*)(x + (size_t)(row0 + r) * 64) + e * 4;
        const float4 a0 = xr[0], a1 = xr[1], a2 = xr[2], a3 = xr[3];
        const float4 av[4] = {a0, a1, a2, a3};
        float d0 = 0.f, d1 = 0.f, d2 = 0.f;
        #pragma unroll
        for (int i = 0; i < 4; ++i) {
            const float4 a = av[i];
            const float4 w0 = *((const float4*)(W + 0 * 1088) + e * 4 + i);
            const float4 w1 = *((const float4*)(W + 1 * 1088) + e * 4 + i);
            const float4 w2 = *((const float4*)(W + 2 * 1088) + e * 4 + i);
            d0 = fmaf(a.w, w0.w, fmaf(a.z, w0.z, fmaf(a.y, w0.y, fmaf(a.x, w0.x, d0))));
            d1 = fmaf(a.w, w1.w, fmaf(a.z, w1.z, fmaf(a.y, w1.y, fmaf(a.x, w1.x, d1))));
            d2 = fmaf(a.w, w2.w, fmaf(a.z, w2.z, fmaf(a.y, w2.y, fmaf(a.x, w2.x, d2))));
        }
        #pragma unroll
        for (int m = 1; m <= 2; m <<= 1) {
            d0 += __shfl_xor(d0, m);
            d1 += __shfl_xor(d1, m);
            d2 += __shfl_xor(d2, m);
        }
        if (e == 0) {
            float* red = (float*)(lds + RED_OFF);
            red[r * 3 + 0] = d0 + bias[0];
            red[r * 3 + 1] = d1 + bias[1];
            red[r * 3 + 2] = d2 + bias[2];
        }
    }
    __syncthreads();   // barrier 1: staging + red seed complete

    // ---- A fragments (lo 32 dims): contiguous b128 stripes ----
    bf16x8 af[8];
    #pragma unroll
    for (int rt = 0; rt < 8; ++rt)
        af[rt] = *(const bf16x8*)(lds + XB_OFF + rt * 1024 + quad * 256 + l15 * 16);

    // ---- pr[rt] = -10*||x_row||^2 per acc element (Gram diag + shfl) ----
    f32x4 pr[8];
    #pragma unroll
    for (int rt = 0; rt < 8; ++rt) {
        const f32x4 d = MFMA(af[rt], af[rt], z, 0, 0, 0);
        f32x4 p;
        #pragma unroll
        for (int reg = 0; reg < 4; ++reg)
            p[reg] = -BETA * __shfl(d[reg], quad * 20 + reg);
        pr[rt] = p;
    }

    // ---- B fragments (20x scaled) + c2r = -10*||c||^2 via scaled Gram ----
    bf16x8 bf[8];
    float c2r[8];
    #pragma unroll
    for (int ct = 0; ct < 8; ++ct) {
        bf[ct] = *(const bf16x8*)(lds + C_OFF + (wv * 8 + ct) * 1024 +
                                  quad * 256 + l15 * 16);
        const f32x4 d = MFMA(bf[ct], bf[ct], z, 0, 0, 0);   // 400*||c||^2
        const float dv = (l15 & 2) ? ((l15 & 1) ? d[3] : d[2])
                                   : ((l15 & 1) ? d[1] : d[0]);
        c2r[ct] = (-BETA / 400.f) * __shfl(dv, (l15 >> 2) * 16 + l15);
    }

    // ---- hot loop: proxy = MFMA(af, 20c, pr); per-ct certificate ----
    #pragma unroll
    for (int ct = 0; ct < 8; ++ct) {
        const bf16x8 b = bf[ct];
        f32x4 mx = {-1e30f, -1e30f, -1e30f, -1e30f};
        #pragma unroll
        for (int rt = 0; rt < 8; ++rt)
            mx = vmax4(mx, MFMA(af[rt], b, pr[rt], 0, 0, 0));
        const float bct = fmaxf(fmaxf(mx[0], mx[1]), fmaxf(mx[2], mx[3])) + c2r[ct];

        if (__builtin_expect(__ballot(bct > THRESH) != 0ull, 0)) {
            // cold: exact fp32, this ct's 16 cols x all 128 rows
            float* red = (float*)(lds + RED_OFF);
            const int j = wv * 128 + ct * 16 + l15;
            const float w0 = W[0 * 1088 + 64 + j];
            const float w1 = W[1 * 1088 + 64 + j];
            const float w2 = W[2 * 1088 + 64 + j];
            const float* cr = centers + (size_t)j * 64;
            #pragma clang loop unroll(disable)
            for (int rr = 0; rr < 32; ++rr) {
                const int r = quad * 32 + rr;
                const float* xr = x + (size_t)(row0 + r) * 64;
                float d2 = 0.f;
                #pragma clang loop unroll(disable)
                for (int k = 0; k < 64; ++k) {
                    const float df = xr[k] - cr[k];
                    d2 = fmaf(df, df, d2);
                }
                const float arg = -BETA * d2;
                if (arg > -87.f) {
                    const float e = expf(arg);
                    atomicAdd(&red[r * 3 + 0], e * w0);
                    atomicAdd(&red[r * 3 + 1], e * w1);
                    atomicAdd(&red[r * 3 + 2], e * w2);
                }
            }
        }
    }
    __syncthreads();   // barrier 2: red final

    // ---- coalesced float4 store ----
    if (tid < 96)
        ((float4*)out)[blockIdx.x * 96 + tid] = *((const float4*)(lds + RED_OFF) + tid);
}

extern "C" void kernel_launch(void* const* d_in, const int* in_sizes, int n_in,
                              void* d_out, int out_size, void* d_ws, size_t ws_size,
                              hipStream_t stream) {
    const float* x       = (const float*)d_in[0];
    const float* centers = (const float*)d_in[1];
    const float* W       = (const float*)d_in[2];
    const float* b       = (const float*)d_in[3];
    float* out = (float*)d_out;

    const int n = in_sizes[0] / 64;   // 65536 rows
    rbfn_fused<<<n / 128, 512, 0, stream>>>(x, centers, W, b, out);
}

// Round 13
// 75.308 us; speedup vs baseline: 1.0132x; 1.0132x over previous
//
#include <hip/hip_runtime.h>
#include <math.h>

typedef short bf16x8 __attribute__((ext_vector_type(8)));
typedef float f32x4 __attribute__((ext_vector_type(4)));
typedef unsigned int uint32;

#define BETA 10.0f
#define THRESH -88.0f
// PER-ELEMENT 32-dim certificate fused into the MFMA (R11/R12-verified):
//   proxy = MFMA(x_bf16, 20*c_bf16, C=-10*||x_r||^2_32); bct = max(proxy) + (-10*||c_j||^2_32)
// = -10*d2_32 + eps, |eps| <= ~10. true arg64 <= bct + 10. Skip when
// bct <= -88 => arg64 <= -78 => contribution <= exp(-78)*1024*0.02 ~ 2e-32.
// P(fire) ~ 1.6e-9/pair -> ~0.1 expected over 67M pairs; firing costs one
// per-ct cold block (16 cols x 128 rows, exact fp32 over all 64 dims).

// LDS map (83 KB -> 1 block/CU; centers staged ONCE per CU)
#define C_OFF    0        // 65536 B: centers lo-32-dim bf16 (x20), chunk layout
#define XB0_OFF  65536    // 8192 B: x tile 0 lo-half bf16 chunk layout
#define XB1_OFF  73728    // 8192 B: x tile 1
#define RED0_OFF 81920    // 1536 B: out accumulator tile 0 [128][3]
#define RED1_OFF 83456    // 1536 B: out accumulator tile 1
#define LDS_TOT  84992

__device__ __forceinline__ uint32 f2bf_rtne(float f) {
    uint32 u = __float_as_uint(f);
    u += 0x7FFFu + ((u >> 16) & 1u);
    return u >> 16;
}
__device__ __forceinline__ uint32 pk_rtne(float a, float b) {
    return f2bf_rtne(a) | (f2bf_rtne(b) << 16);
}
__device__ __forceinline__ f32x4 vmax4(f32x4 a, f32x4 b) {
    f32x4 r;
    r[0] = fmaxf(a[0], b[0]); r[1] = fmaxf(a[1], b[1]);
    r[2] = fmaxf(a[2], b[2]); r[3] = fmaxf(a[3], b[3]);
    return r;
}
#define MFMA __builtin_amdgcn_mfma_f32_16x16x32_bf16

// Persistent block = 256 rows (2 tiles of 128) x 1024 centers. Grid 256 =
// 1 block/CU. 512 thr = 8 waves; wave = all 128 rows x 128-col group.
// Staging (centers + both x tiles + both Wx passes) happens before ONE
// barrier; bf/c2r computed once and reused across both tiles.
__global__ __launch_bounds__(512, 2) void rbfn_fused(
    const float* __restrict__ x,
    const float* __restrict__ centers,
    const float* __restrict__ W,
    const float* __restrict__ bias,
    float* __restrict__ out)
{
    __shared__ __align__(16) char lds[LDS_TOT];

    const int tid = threadIdx.x;
    const int wv = tid >> 6;
    const int lane = tid & 63;
    const int quad = lane >> 4;
    const int l15 = lane & 15;
    const int row0 = blockIdx.x * 256;
    const f32x4 z = {0.f, 0.f, 0.f, 0.f};

    // ---- stage centers lo-half, PRE-SCALED by 20 -> bf16 chunk layout ----
    #pragma unroll
    for (int i = 0; i < 16; ++i) {
        const int f = i * 512 + tid;
        const int j = f >> 3, sg = f & 7;
        const float4 v = *((const float4*)centers + j * 16 + sg);
        uint2 q;
        q.x = pk_rtne(20.f * v.x, 20.f * v.y);
        q.y = pk_rtne(20.f * v.z, 20.f * v.w);
        *(uint2*)(lds + C_OFF + (j >> 4) * 1024 + (sg >> 1) * 256 +
                  (j & 15) * 16 + (sg & 1) * 8) = q;
    }
    // ---- stage BOTH x tiles' lo-halves -> bf16 chunk layout ----
    #pragma unroll
    for (int t = 0; t < 2; ++t) {
        const int xb = t ? XB1_OFF : XB0_OFF;
        #pragma unroll
        for (int i = 0; i < 2; ++i) {
            const int f = i * 512 + tid;
            const int r = f >> 3, sg = f & 7;
            const float4 v = *((const float4*)(x + (size_t)(row0 + t * 128) * 64) + r * 16 + sg);
            uint2 q; q.x = pk_rtne(v.x, v.y); q.y = pk_rtne(v.z, v.w);
            *(uint2*)(lds + xb + (r >> 4) * 1024 + (sg >> 1) * 256 +
                      (r & 15) * 16 + (sg & 1) * 8) = q;
        }
    }

    // ---- exact fp32 x@Wx^T + bias -> red0/red1 (global reads, coalesced) ----
    #pragma unroll
    for (int t = 0; t < 2; ++t) {
        const int r = tid >> 2, e = tid & 3;
        const float4* xr = (const float4*)(x + (size_t)(row0 + t * 128 + r) * 64) + e * 4;
        const float4 a0 = xr[0], a1 = xr[1], a2 = xr[2], a3 = xr[3];
        const float4 av[4] = {a0, a1, a2, a3};
        float d0 = 0.f, d1 = 0.f, d2 = 0.f;
        #pragma unroll
        for (int i = 0; i < 4; ++i) {
            const float4 a = av[i];
            const float4 w0 = *((const float4*)(W + 0 * 1088) + e * 4 + i);
            const float4 w1 = *((const float4*)(W + 1 * 1088) + e * 4 + i);
            const float4 w2 = *((const float4*)(W + 2 * 1088) + e * 4 + i);
            d0 = fmaf(a.w, w0.w, fmaf(a.z, w0.z, fmaf(a.y, w0.y, fmaf(a.x, w0.x, d0))));
            d1 = fmaf(a.w, w1.w, fmaf(a.z, w1.z, fmaf(a.y, w1.y, fmaf(a.x, w1.x, d1))));
            d2 = fmaf(a.w, w2.w, fmaf(a.z, w2.z, fmaf(a.y, w2.y, fmaf(a.x, w2.x, d2))));
        }
        #pragma unroll
        for (int m = 1; m <= 2; m <<= 1) {
            d0 += __shfl_xor(d0, m);
            d1 += __shfl_xor(d1, m);
            d2 += __shfl_xor(d2, m);
        }
        if (e == 0) {
            float* red = (float*)(lds + (t ? RED1_OFF : RED0_OFF));
            red[r * 3 + 0] = d0 + bias[0];
            red[r * 3 + 1] = d1 + bias[1];
            red[r * 3 + 2] = d2 + bias[2];
        }
    }
    __syncthreads();   // barrier 1: all staging + red seeds complete

    // ---- B fragments (20x) + c2r via scaled Gram diagonal — ONCE ----
    bf16x8 bf[8];
    float c2r[8];
    #pragma unroll
    for (int ct = 0; ct < 8; ++ct) {
        bf[ct] = *(const bf16x8*)(lds + C_OFF + (wv * 8 + ct) * 1024 +
                                  quad * 256 + l15 * 16);
        const f32x4 d = MFMA(bf[ct], bf[ct], z, 0, 0, 0);   // 400*||c||^2
        const float dv = (l15 & 2) ? ((l15 & 1) ? d[3] : d[2])
                                   : ((l15 & 1) ? d[1] : d[0]);
        c2r[ct] = (-BETA / 400.f) * __shfl(dv, (l15 >> 2) * 16 + l15);
    }

    // ---- two row-tiles, reusing bf/c2r ----
    #pragma unroll
    for (int t = 0; t < 2; ++t) {
        const int xb = t ? XB1_OFF : XB0_OFF;
        float* red = (float*)(lds + (t ? RED1_OFF : RED0_OFF));

        bf16x8 af[8];
        #pragma unroll
        for (int rt = 0; rt < 8; ++rt)
            af[rt] = *(const bf16x8*)(lds + xb + rt * 1024 + quad * 256 + l15 * 16);

        f32x4 pr[8];
        #pragma unroll
        for (int rt = 0; rt < 8; ++rt) {
            const f32x4 d = MFMA(af[rt], af[rt], z, 0, 0, 0);
            f32x4 p;
            #pragma unroll
            for (int reg = 0; reg < 4; ++reg)
                p[reg] = -BETA * __shfl(d[reg], quad * 20 + reg);
            pr[rt] = p;
        }

        // hot loop: proxy = MFMA(af, 20c, pr); per-ct certificate
        #pragma unroll
        for (int ct = 0; ct < 8; ++ct) {
            const bf16x8 b = bf[ct];
            f32x4 mx = {-1e30f, -1e30f, -1e30f, -1e30f};
            #pragma unroll
            for (int rt = 0; rt < 8; ++rt)
                mx = vmax4(mx, MFMA(af[rt], b, pr[rt], 0, 0, 0));
            const float bct = fmaxf(fmaxf(mx[0], mx[1]), fmaxf(mx[2], mx[3])) + c2r[ct];

            if (__builtin_expect(__ballot(bct > THRESH) != 0ull, 0)) {
                // cold: exact fp32, this ct's 16 cols x this tile's 128 rows
                const int j = wv * 128 + ct * 16 + l15;
                const float w0 = W[0 * 1088 + 64 + j];
                const float w1 = W[1 * 1088 + 64 + j];
                const float w2 = W[2 * 1088 + 64 + j];
                const float* cr = centers + (size_t)j * 64;
                #pragma clang loop unroll(disable)
                for (int rr = 0; rr < 32; ++rr) {
                    const int r = quad * 32 + rr;
                    const float* xr = x + (size_t)(row0 + t * 128 + r) * 64;
                    float d2 = 0.f;
                    #pragma clang loop unroll(disable)
                    for (int k = 0; k < 64; ++k) {
                        const float df = xr[k] - cr[k];
                        d2 = fmaf(df, df, d2);
                    }
                    const float arg = -BETA * d2;
                    if (arg > -87.f) {
                        const float e = expf(arg);
                        atomicAdd(&red[r * 3 + 0], e * w0);
                        atomicAdd(&red[r * 3 + 1], e * w1);
                        atomicAdd(&red[r * 3 + 2], e * w2);
                    }
                }
            }
        }
    }
    __syncthreads();   // barrier 2: both red buffers final

    // ---- coalesced float4 stores (192 float4s per block) ----
    if (tid < 96) {
        ((float4*)out)[blockIdx.x * 192 + tid] =
            *((const float4*)(lds + RED0_OFF) + tid);
        ((float4*)out)[blockIdx.x * 192 + 96 + tid] =
            *((const float4*)(lds + RED1_OFF) + tid);
    }
}

extern "C" void kernel_launch(void* const* d_in, const int* in_sizes, int n_in,
                              void* d_out, int out_size, void* d_ws, size_t ws_size,
                              hipStream_t stream) {
    const float* x       = (const float*)d_in[0];
    const float* centers = (const float*)d_in[1];
    const float* W       = (const float*)d_in[2];
    const float* b       = (const float*)d_in[3];
    float* out = (float*)d_out;

    const int n = in_sizes[0] / 64;   // 65536 rows
    rbfn_fused<<<n / 256, 512, 0, stream>>>(x, centers, W, b, out);
}